// Round 6
// baseline (351.567 us; speedup 1.0000x reference)
//
#include <hip/hip_runtime.h>

// DualModel3 R6: pre-transpose W1 to bf16 [O*H][K] in d_ws, then a
// zero-LDS, zero-barrier MFMA GEMM whose operands are single dwordx4
// loads in fragment layout. R5 lesson: the in-LDS transpose of W1's
// h-inner layout made the kernel LDS-instruction-bound (~2.8k of 3.25k
// cyc/CU/iter on the LDS pipe). Moving the transpose to one HBM pass
// removes LDS (and all K-loop barriers) from the hot kernel entirely.
//
// prep (5376 blocks): fcW -> bf16 rows 0..1023 (1000.. zero-padded),
//   x -> bf16, W1 [o][k][h] -> W1t row n=o*4+h, k-contiguous bf16.
// main (544 blocks x 256): wave = 32m x 64n, block = 4 waves stacked in m
//   (128m x 64n). A-frag: xb row m0+w*32+l31, 16B at k. B-frag: W1t row n.
//   mfma_f32_32x32x16_bf16, depth-2 register pipeline, no __syncthreads
//   in the K-loop => no vmcnt(0) drains. C/D: col=lane&31,
//   row=(r&3)+8*(r>>2)+4*(lane>>5) [m74/m101; R5-verified]. Decoder
//   epilogue: bias+leaky-relu+W2 H-reduce (shfl_xor 1,2), LDS-staged
//   full-line x2 stores. Fallback to the R5 kernel if ws too small.

typedef __bf16 bf16_t;
typedef __bf16 bf16x4 __attribute__((ext_vector_type(4)));
typedef __bf16 bf16x8 __attribute__((ext_vector_type(8)));
typedef float  f32x4  __attribute__((ext_vector_type(4)));
typedef float  f32x16 __attribute__((ext_vector_type(16)));

#define FCW_OFF  0ull
#define W1T_OFF  4194304ull                 // 1024*4096
#define XB_OFF   71303168ull                // + 16384*4096
#define WS_NEED  72351744ull                // + 256*4096

// ---------------- prep: convert + transpose into ws ----------------
__global__ __launch_bounds__(256)
void prep(const float* __restrict__ x, const float* __restrict__ fcW,
          const float* __restrict__ W1, char* __restrict__ ws)
{
    __shared__ bf16_t shT[8192];            // 16 KB, transpose staging
    const int tid = threadIdx.x, bid = blockIdx.x;

    if (bid < 1280) {                       // fcW rows (0..1023) and x rows
        const bool isx = (bid >= 1024);
        const int row = isx ? bid - 1024 : bid;
        const float* src = isx ? (x + row * 2048) : (fcW + row * 2048);
        char* dst = ws + (isx ? XB_OFF : FCW_OFF) + (size_t)row * 4096 + tid * 16;
        bf16x8 v;
        if (!isx && row >= 1000) {
            #pragma unroll
            for (int c = 0; c < 8; ++c) v[c] = (bf16_t)0.f;
        } else {
            f32x4 u0 = *(const f32x4*)(src + tid * 8);
            f32x4 u1 = *(const f32x4*)(src + tid * 8 + 4);
            #pragma unroll
            for (int c = 0; c < 4; ++c) { v[c] = (bf16_t)u0[c]; v[4 + c] = (bf16_t)u1[c]; }
        }
        *(bf16x8*)dst = v;
        return;
    }
    // W1 transpose: one o per block. in [2048][4] f32 -> out [4][2048] bf16
    const int o = bid - 1280;
    const f32x4* src = (const f32x4*)(W1 + (size_t)o * 8192);
    #pragma unroll
    for (int j = 0; j < 8; ++j) {
        const int k = tid + j * 256;
        f32x4 u = src[k];
        #pragma unroll
        for (int h = 0; h < 4; ++h) shT[h * 2048 + k] = (bf16_t)u[h];
    }
    __syncthreads();
    const int h = tid >> 6, l = tid & 63;
    char* dst = ws + W1T_OFF + (size_t)(o * 4 + h) * 4096;
    #pragma unroll
    for (int j = 0; j < 4; ++j) {
        const int k0 = j * 512 + l * 8;
        bf16x8 v = *(const bf16x8*)(&shT[h * 2048 + k0]);
        *(bf16x8*)(dst + k0 * 2) = v;
    }
}

// ---------------- main: zero-LDS barrier-free GEMM ----------------
__global__ __launch_bounds__(256, 2)
void gemm_main(const char* __restrict__ ws,
               const float* __restrict__ fcb,
               const float* __restrict__ b1,
               const float* __restrict__ W2,
               const float* __restrict__ b2,
               float* __restrict__ out)
{
    __shared__ float xs[2048];              // epilogue staging only (8 KB)

    const int tid = threadIdx.x;
    const int lane = tid & 63, w = tid >> 6;
    const int l31 = lane & 31, half = lane >> 5;

    // XCD swizzle: wids x*68..x*68+67 on XCD x -> both m-siblings of a
    // column panel co-resident (W1t HBM-read once, L2-read for sibling).
    const int idx = blockIdx.x;
    const int wid = (idx & 7) * 68 + (idx >> 3);
    const int cg = wid >> 1, rg = wid & 1, m0 = rg * 128;
    const bool is_fc = (cg < 16);
    const int c0 = (is_fc ? cg : cg - 16) * 64;

    const char* bb = is_fc ? (ws + FCW_OFF + (size_t)c0 * 4096)
                           : (ws + W1T_OFF + (size_t)c0 * 4096);
    const char* aP  = ws + XB_OFF + (size_t)(m0 + w * 32 + l31) * 4096 + half * 16;
    const char* bP0 = bb + (size_t)l31 * 4096 + half * 16;
    const char* bP1 = bb + (size_t)(32 + l31) * 4096 + half * 16;

    f32x16 acc0, acc1;
    #pragma unroll
    for (int r = 0; r < 16; ++r) { acc0[r] = 0.f; acc1[r] = 0.f; }

    bf16x8 aC  = *(const bf16x8*)aP;
    bf16x8 b0C = *(const bf16x8*)bP0;
    bf16x8 b1C = *(const bf16x8*)bP1;
    #pragma unroll 4
    for (int kt = 0; kt < 127; ++kt) {
        const int off = (kt + 1) * 32;      // 16 k's * 2B
        bf16x8 aN  = *(const bf16x8*)(aP + off);
        bf16x8 b0N = *(const bf16x8*)(bP0 + off);
        bf16x8 b1N = *(const bf16x8*)(bP1 + off);
        acc0 = __builtin_amdgcn_mfma_f32_32x32x16_bf16(aC, b0C, acc0, 0, 0, 0);
        acc1 = __builtin_amdgcn_mfma_f32_32x32x16_bf16(aC, b1C, acc1, 0, 0, 0);
        aC = aN; b0C = b0N; b1C = b1N;
    }
    acc0 = __builtin_amdgcn_mfma_f32_32x32x16_bf16(aC, b0C, acc0, 0, 0, 0);
    acc1 = __builtin_amdgcn_mfma_f32_32x32x16_bf16(aC, b1C, acc1, 0, 0, 0);

    // ---- epilogue ----  C/D: col=lane&31, row=(r&3)+8*(r>>2)+4*half
    if (is_fc) {
        #pragma unroll
        for (int j = 0; j < 2; ++j) {
            const int c = c0 + j * 32 + l31;
            const bool valid = (c < 1000);
            const float bias = fcb[valid ? c : 999];
            const f32x16& a = j ? acc1 : acc0;
            #pragma unroll
            for (int r = 0; r < 16; ++r) {
                if (valid) {
                    const int m = m0 + w * 32 + (r & 3) + 8 * (r >> 2) + 4 * half;
                    out[m * 1000 + c] = a[r] + bias;
                }
            }
        }
    } else {
        float* x2 = out + 256 * 1000;
        const int o0 = (cg - 16) * 16;
        #pragma unroll
        for (int j = 0; j < 2; ++j) {
            const int c = c0 + j * 32 + l31;          // [0,16384)
            const float b1v = b1[c], w2v = W2[c];
            const float b2v = b2[c >> 2];
            const int o_loc = (j * 32 + l31) >> 2;    // 0..15
            const f32x16& a = j ? acc1 : acc0;
            #pragma unroll
            for (int r = 0; r < 16; ++r) {
                float h = a[r] + b1v;
                h = (h >= 0.f) ? h : 0.1f * h;        // leaky relu
                float wv = h * w2v;
                wv += __shfl_xor(wv, 1, 64);          // decoder's 4 h-cols
                wv += __shfl_xor(wv, 2, 64);
                if ((lane & 3) == 0) {
                    const int rl = w * 32 + (r & 3) + 8 * (r >> 2) + 4 * half;
                    xs[rl * 16 + o_loc] = wv + b2v;
                }
            }
        }
        __syncthreads();
        // full-line stores: 2 threads cover one row's 64B
        const int row = tid >> 1, part = tid & 1;
        f32x4 v0 = *(const f32x4*)(xs + row * 16 + part * 8);
        f32x4 v1 = *(const f32x4*)(xs + row * 16 + part * 8 + 4);
        float* dst = x2 + (size_t)(m0 + row) * 4096 + o0 + part * 8;
        *(f32x4*)dst = v0;
        *(f32x4*)(dst + 4) = v1;
    }
}

// ---------------- fallback (R5 kernel, used when ws too small) ----------------
__global__ __launch_bounds__(256, 2)
void fused_dual_fb(const float* __restrict__ x, const float* __restrict__ fcW,
                   const float* __restrict__ fcb, const float* __restrict__ W1,
                   const float* __restrict__ b1, const float* __restrict__ W2,
                   const float* __restrict__ b2, float* __restrict__ out)
{
    __shared__ __align__(16) char lA[128 * 128];
    __shared__ __align__(16) char lB[64 * 128];

    const int tid = threadIdx.x;
    const int lane = tid & 63, w = tid >> 6;
    const int l31 = lane & 31, half = lane >> 5;
    const int idx = blockIdx.x;
    const int wid = (idx & 7) * 68 + (idx >> 3);
    const int cg = wid >> 1, rg = wid & 1, m0 = rg * 128;
    const bool is_fc = (cg < 16);
    const int c0 = (is_fc ? cg : cg - 16) * 64;

    const int arow = tid >> 2;
    const int aq = tid & 3;
    const float* aBase = x + (m0 + arow) * 2048 + aq * 4;
    const float* bBase;
    if (is_fc) {
        int rowc = c0 + arow; if (rowc > 999) rowc = 999;
        bBase = fcW + rowc * 2048 + aq * 4;
    } else {
        bBase = W1 + ((c0 >> 2) + w * 4) * 8192 + lane * 4;
    }
    f32x4 aR[8], bR[4];
    auto LOAD = [&](int kt) {
        const float* ap = aBase + kt * 64;
        #pragma unroll
        for (int j = 0; j < 8; ++j)
            aR[j] = *(const f32x4*)(ap + (j & 1) * (64 * 2048) + (j >> 1) * 16);
        if (is_fc) {
            const float* bp = bBase + kt * 64;
            #pragma unroll
            for (int j = 0; j < 4; ++j) bR[j] = *(const f32x4*)(bp + j * 16);
        } else {
            const float* bp = bBase + kt * 256;
            #pragma unroll
            for (int q = 0; q < 4; ++q) bR[q] = *(const f32x4*)(bp + q * 8192);
        }
    };
    auto STAGE = [&]() {
        #pragma unroll
        for (int j = 0; j < 8; ++j) {
            const int r = arow + 64 * (j & 1);
            const int kb = aq * 8 + (j >> 1) * 32;
            const int ad = r * 128 + (((kb >> 4) ^ (r & 7)) << 4) + (kb & 15);
            bf16x4 v;
            #pragma unroll
            for (int c = 0; c < 4; ++c) v[c] = (bf16_t)aR[j][c];
            *(bf16x4*)(lA + ad) = v;
        }
        if (is_fc) {
            #pragma unroll
            for (int j = 0; j < 4; ++j) {
                const int kb = aq * 8 + j * 32;
                const int ad = arow * 128 + (((kb >> 4) ^ (arow & 7)) << 4) + (kb & 15);
                bf16x4 v;
                #pragma unroll
                for (int c = 0; c < 4; ++c) v[c] = (bf16_t)bR[j][c];
                *(bf16x4*)(lB + ad) = v;
            }
        } else {
            const int gsub = ((lane >> 3) << 4) + (lane & 7) * 2;
            #pragma unroll
            for (int q = 0; q < 4; ++q)
            #pragma unroll
            for (int h = 0; h < 4; ++h) {
                const int n = w * 16 + q * 4 + h;
                const int ad = n * 128 + (gsub ^ ((n & 7) << 4));
                *(bf16_t*)(lB + ad) = (bf16_t)bR[q][h];
            }
        }
    };
    const int mh = (w & 1) * 64, nh = (w >> 1) * 32;
    f32x16 acc[2];
    #pragma unroll
    for (int i = 0; i < 2; ++i)
        #pragma unroll
        for (int r = 0; r < 16; ++r) acc[i][r] = 0.f;
    LOAD(0);
    for (int kt = 0; kt < 32; ++kt) {
        __syncthreads();
        STAGE();
        __syncthreads();
        if (kt != 31) LOAD(kt + 1);
        const int nrow = nh + l31;
        #pragma unroll
        for (int ks = 0; ks < 4; ++ks) {
            const int g = ks * 2 + half;
            bf16x8 bf = *(const bf16x8*)(lB + nrow * 128 + ((g ^ (nrow & 7)) << 4));
            #pragma unroll
            for (int i = 0; i < 2; ++i) {
                const int mrow = mh + i * 32 + l31;
                bf16x8 af = *(const bf16x8*)(lA + mrow * 128 + ((g ^ (mrow & 7)) << 4));
                acc[i] = __builtin_amdgcn_mfma_f32_32x32x16_bf16(af, bf, acc[i], 0, 0, 0);
            }
        }
    }
    if (is_fc) {
        const int c = c0 + nh + l31;
        const bool valid = (c < 1000);
        const float bias = fcb[valid ? c : 999];
        #pragma unroll
        for (int i = 0; i < 2; ++i)
        #pragma unroll
        for (int r = 0; r < 16; ++r) {
            if (valid) {
                const int m = m0 + mh + i * 32 + (r & 3) + 8 * (r >> 2) + 4 * half;
                out[m * 1000 + c] = acc[i][r] + bias;
            }
        }
    } else {
        float* x2 = out + 256 * 1000;
        const int d = cg - 16;
        const int n_glob = c0 + nh + l31;
        const float b1v = b1[n_glob], w2v = W2[n_glob];
        const float b2v = b2[n_glob >> 2];
        __syncthreads();
        float* xs2 = (float*)lA;
        const int o_loc = (nh + l31) >> 2;
        #pragma unroll
        for (int i = 0; i < 2; ++i)
        #pragma unroll
        for (int r = 0; r < 16; ++r) {
            float h = acc[i][r] + b1v;
            h = (h >= 0.f) ? h : 0.1f * h;
            float wv = h * w2v;
            wv += __shfl_xor(wv, 1, 64);
            wv += __shfl_xor(wv, 2, 64);
            if ((lane & 3) == 0) {
                const int row = mh + i * 32 + (r & 3) + 8 * (r >> 2) + 4 * half;
                xs2[row * 16 + o_loc] = wv + b2v;
            }
        }
        __syncthreads();
        #pragma unroll
        for (int j = 0; j < 2; ++j) {
            const int row = (tid >> 2) + 64 * j, part = tid & 3;
            f32x4 v = *(const f32x4*)(xs2 + row * 16 + part * 4);
            *(f32x4*)(x2 + (m0 + row) * 4096 + d * 16 + part * 4) = v;
        }
    }
}

extern "C" void kernel_launch(void* const* d_in, const int* in_sizes, int n_in,
                              void* d_out, int out_size, void* d_ws, size_t ws_size,
                              hipStream_t stream)
{
    (void)in_sizes; (void)n_in; (void)out_size;
    const float* x   = (const float*)d_in[0];
    const float* fcW = (const float*)d_in[1];
    const float* fcb = (const float*)d_in[2];
    const float* W1  = (const float*)d_in[3];
    const float* b1  = (const float*)d_in[4];
    const float* W2  = (const float*)d_in[5];
    const float* b2  = (const float*)d_in[6];
    if (ws_size >= WS_NEED) {
        prep<<<5376, 256, 0, stream>>>(x, fcW, W1, (char*)d_ws);
        gemm_main<<<544, 256, 0, stream>>>((const char*)d_ws, fcb, b1, W2, b2, (float*)d_out);
    } else {
        fused_dual_fb<<<544, 256, 0, stream>>>(x, fcW, fcb, W1, b1, W2, b2, (float*)d_out);
    }
}